// Round 6
// baseline (106.382 us; speedup 1.0000x reference)
//
#include <hip/hip_runtime.h>

// Submanifold sparse 3D conv — v6: TR=64 rows/wave (4 subtiles share W reads),
// zero-row trick (no masking), reg-staged W double-buffer, raw barriers with
// lgkmcnt-only drains (vmem prefetches stay in flight across barriers).
//
// Map identity (verified R1-R4): out[imap[m,p]] += feats[omap[m,p]] @ kernel[26-kk(m)]
// tab[m][tile64][64] = src row (omap) or N (zero row), built from sorted imap.
// fb has N+1 rows; row N is all zeros.

#define CIN 64
#define COUT 64
#define TR 64
#define NOFF 26

typedef short bf16x8 __attribute__((ext_vector_type(8)));
typedef unsigned short ushort8 __attribute__((ext_vector_type(8)));
typedef float f32x4 __attribute__((ext_vector_type(4)));

__device__ inline unsigned short bfbits(float f) {
    unsigned u = __builtin_bit_cast(unsigned, f);
    u += 0x7fffu + ((u >> 16) & 1u);          // RNE
    return (unsigned short)(u >> 16);
}

__device__ inline int kk_of_item(int i) {
    return (i >= 26) ? 13 : 26 - (i < 13 ? i : i + 1);
}

// ---------- prepass 1: feats f32 -> bf16 ----------------------------------
__global__ __launch_bounds__(256) void prep_feats(const float* __restrict__ f,
                                                  unsigned short* __restrict__ fb,
                                                  int n) {
    const int i8 = (blockIdx.x * 256 + threadIdx.x) * 8;
    if (i8 >= n) return;
    const float4 v0 = *(const float4*)(f + i8);
    const float4 v1 = *(const float4*)(f + i8 + 4);
    union { unsigned short u[8]; bf16x8 v; } r;
    r.u[0] = bfbits(v0.x); r.u[1] = bfbits(v0.y);
    r.u[2] = bfbits(v0.z); r.u[3] = bfbits(v0.w);
    r.u[4] = bfbits(v1.x); r.u[5] = bfbits(v1.y);
    r.u[6] = bfbits(v1.z); r.u[7] = bfbits(v1.w);
    *(bf16x8*)(fb + i8) = r.v;
}

// ---------- prepass 2: W [27][c][o] f32 -> Wt [27][o][c] bf16, PRE-SWIZZLED
__global__ __launch_bounds__(256) void prep_wt(const float* __restrict__ W,
                                               unsigned short* __restrict__ Wt) {
    const int k = blockIdx.x;
    for (int idx = threadIdx.x; idx < CIN * COUT; idx += 256) {
        const int c = idx >> 6, o = idx & 63;
        const int q = c >> 3, e = c & 7;
        Wt[((k * 64 + o) * 64) + (((q ^ (o & 7)) << 3) + e)] =
            bfbits(W[(k * 64 + c) * 64 + o]);
    }
}

// ---------- prepass 3: tab init (value N) + scatter -----------------------
__global__ __launch_bounds__(256) void prep_tab_init(int4* __restrict__ tab4,
                                                     int n4, int N) {
    const int i = blockIdx.x * 256 + threadIdx.x;
    if (i < n4) tab4[i] = make_int4(N, N, N, N);
}

__global__ __launch_bounds__(256) void prep_tab(const int* __restrict__ imap,
                                                const int* __restrict__ omap,
                                                int P, int nt,
                                                int* __restrict__ tab) {
    const int p = blockIdx.x * 256 + threadIdx.x;
    const int m = blockIdx.y;
    if (p >= P) return;
    const int iv = imap[(size_t)m * P + p];
    if (iv < 0) return;
    tab[((size_t)m * nt + (iv >> 6)) * TR + (iv & 63)] = omap[(size_t)m * P + p];
}

// ---------- main ----------------------------------------------------------
__global__ __launch_bounds__(256) void spconv_v6(
    const unsigned short* __restrict__ fb,   // feats bf16 [N+1][64], row N = 0
    const unsigned short* __restrict__ wt,   // [27][64][64] bf16, pre-swizzled
    const int* __restrict__ tab,             // [26][nt][64], empties = N
    float* __restrict__ out, int N, int nt)
{
    __shared__ unsigned short wbuf[2][4096]; // 2 x 8KB double buffer

    const int tid = threadIdx.x, w = tid >> 6, lane = tid & 63;
    const int col = lane & 15, grp = lane >> 4;
    const int t = blockIdx.x * 4 + w;        // this wave's 64-row tile
    const int tt = (t < nt) ? t : (nt - 1);
    const int r0 = t * TR;
    const size_t tstep = (size_t)nt * TR;

    const int* tb0 = tab + (size_t)tt * TR + col;   // item-0 tab base for this lane

    // resolve sv[4] for item j given raw tab values tv[4]
    auto resolve = [&](int j, const int* tv, int* sv) {
#pragma unroll
        for (int s = 0; s < 4; ++s) {
            int v;
            if (j < 26) v = tv[s];
            else if (j == 26) { const int r = r0 + s * 16 + col; v = (r < N) ? r : N; }
            else v = N;
            sv[s] = v;
        }
    };

    // --- prologue: tab pipeline depth 2 ---
    int t0[4], t1[4], tv2[4];
#pragma unroll
    for (int s = 0; s < 4; ++s) {
        t0[s]  = tb0[s * 16];
        t1[s]  = (tb0 + tstep)[s * 16];
        tv2[s] = (tb0 + 2 * tstep)[s * 16];
    }
    int sv_c[4], sv_n[4];
    resolve(0, t0, sv_c);
    resolve(1, t1, sv_n);

    bf16x8 a_cur[4][2], a_nx[4][2];
#pragma unroll
    for (int s = 0; s < 4; ++s) {
        const bf16x8* fp = (const bf16x8*)(fb + (size_t)sv_c[s] * 64 + grp * 8);
        a_cur[s][0] = fp[0];
        a_cur[s][1] = fp[4];
    }

    // stage W(item 0): linear copy (source pre-swizzled), 32B/lane
    {
        const unsigned short* wk = wt + kk_of_item(0) * 4096;
        const ushort8 wl0 = *(const ushort8*)(wk + tid * 8);
        const ushort8 wl1 = *(const ushort8*)(wk + 2048 + tid * 8);
        *(ushort8*)(&wbuf[0][tid * 8]) = wl0;
        *(ushort8*)(&wbuf[0][2048 + tid * 8]) = wl1;
    }
    asm volatile("s_waitcnt lgkmcnt(0)" ::: "memory");
    __builtin_amdgcn_s_barrier();

    f32x4 acc[4][4];
#pragma unroll
    for (int s = 0; s < 4; ++s)
#pragma unroll
        for (int ot = 0; ot < 4; ++ot) acc[s][ot] = {0.f, 0.f, 0.f, 0.f};

    for (int it = 0; it < 27; ++it) {
        // (1) next item's W -> regs (global, L2-hot)
        const unsigned short* wkn = wt + kk_of_item(it + 1) * 4096;
        const ushort8 wl0 = *(const ushort8*)(wkn + tid * 8);
        const ushort8 wl1 = *(const ushort8*)(wkn + 2048 + tid * 8);

        // (2) next item's gather (always-valid rows; row N is zeros)
#pragma unroll
        for (int s = 0; s < 4; ++s) {
            const bf16x8* fp = (const bf16x8*)(fb + (size_t)sv_n[s] * 64 + grp * 8);
            a_nx[s][0] = fp[0];
            a_nx[s][1] = fp[4];
        }

        // (3) tab pipeline: resolve it+2 from tv2, issue it+3 (clamped)
        int sv_nn[4];
        resolve(it + 2, tv2, sv_nn);
        {
            const int j3 = (it + 3 < 26) ? it + 3 : 25;
            const int* tb3 = tb0 + (size_t)j3 * tstep;
#pragma unroll
            for (int s = 0; s < 4; ++s) tv2[s] = tb3[s * 16];
        }

        // (4) compute: 8 ds_read_b128 (swizzled, conflict-free) + 32 MFMA
        const unsigned short* cb = wbuf[it & 1];
        __builtin_amdgcn_s_setprio(1);
#pragma unroll
        for (int ot = 0; ot < 4; ++ot) {
            const int o = ot * 16 + col;
            const bf16x8 b0 = *(const bf16x8*)(cb + o * 64 + ((grp ^ (col & 7)) << 3));
            const bf16x8 b1 = *(const bf16x8*)(cb + o * 64 + (((4 + grp) ^ (col & 7)) << 3));
#pragma unroll
            for (int s = 0; s < 4; ++s) {
                acc[s][ot] = __builtin_amdgcn_mfma_f32_16x16x32_bf16(a_cur[s][0], b0, acc[s][ot], 0, 0, 0);
                acc[s][ot] = __builtin_amdgcn_mfma_f32_16x16x32_bf16(a_cur[s][1], b1, acc[s][ot], 0, 0, 0);
            }
        }
        __builtin_amdgcn_s_setprio(0);

        // (5) stage next W into the other buffer
        unsigned short* nb = wbuf[(it + 1) & 1];
        *(ushort8*)(&nb[tid * 8]) = wl0;
        *(ushort8*)(&nb[2048 + tid * 8]) = wl1;

        // (6) raw barrier: drain LDS only; vmem prefetches stay in flight
        asm volatile("s_waitcnt lgkmcnt(0)" ::: "memory");
        __builtin_amdgcn_s_barrier();

        // (7) rotate
#pragma unroll
        for (int s = 0; s < 4; ++s) {
            sv_c[s] = sv_n[s];
            sv_n[s] = sv_nn[s];
            a_cur[s][0] = a_nx[s][0];
            a_cur[s][1] = a_nx[s][1];
        }
    }

    // --- write-out (one plain store per element) ---
#pragma unroll
    for (int s = 0; s < 4; ++s)
#pragma unroll
        for (int ot = 0; ot < 4; ++ot) {
            const f32x4 cv = acc[s][ot];
#pragma unroll
            for (int reg = 0; reg < 4; ++reg) {
                const int r = r0 + s * 16 + grp * 4 + reg;
                if (r < N) out[(size_t)r * 64 + ot * 16 + col] = cv[reg];
            }
        }
}

// ---------- fallback (fp32 + atomics, round-0) ----------------------------
template <int MODE>
__global__ __launch_bounds__(256) void spconv_fb(
    const float* __restrict__ feats, const float* __restrict__ W,
    const int* __restrict__ imap, const int* __restrict__ omap,
    float* __restrict__ out, int npairs)
{
    __shared__ float4 wt4[16 * 64];
    const int tid = threadIdx.x, koff = blockIdx.y;
    const float* Wk;
    const int* im = nullptr; const int* om = nullptr;
    if (MODE == 0) Wk = W + 13 * (CIN * COUT);
    else {
        const int kk = (koff < 13) ? koff : koff + 1;
        Wk = W + (size_t)kk * (CIN * COUT);
        im = imap + (size_t)koff * npairs; om = omap + (size_t)koff * npairs;
    }
    float* wts = (float*)wt4;
    for (int idx = tid; idx < CIN * COUT; idx += 256) {
        const int c = idx >> 6, o = idx & 63;
        wts[((c >> 2) * 64 + o) * 4 + (c & 3)] = Wk[idx];
    }
    __syncthreads();
    const int o = tid & 63, w = tid >> 6;
    const int base = blockIdx.x * 256 + w * 64;
    const float4* f4p = (const float4*)feats;
    for (int n = 0; n < 64; ++n) {
        const int p = base + n;
        if (p >= npairs) break;
        int i, j;
        if (MODE == 0) { i = p; j = p; }
        else { i = im[p]; if (i < 0) continue; j = om[p]; }
        i = __builtin_amdgcn_readfirstlane(i);
        float a = 0.f;
#pragma unroll
        for (int c4 = 0; c4 < 16; ++c4) {
            const float4 f = f4p[(size_t)i * 16 + c4];
            const float4 wv = wt4[c4 * 64 + o];
            a += f.x * wv.x + f.y * wv.y + f.z * wv.z + f.w * wv.w;
        }
        if (MODE == 0) out[(size_t)j * COUT + o] = a;
        else atomicAdd(&out[(size_t)j * COUT + o], a);
    }
}

extern "C" void kernel_launch(void* const* d_in, const int* in_sizes, int n_in,
                              void* d_out, int out_size, void* d_ws, size_t ws_size,
                              hipStream_t stream) {
    const float* feats = (const float*)d_in[0];
    const float* W     = (const float*)d_in[1];
    const int* imap    = (const int*)d_in[2];
    const int* omap    = (const int*)d_in[3];
    float* out         = (float*)d_out;

    const int N = in_sizes[0] / CIN;
    const int P = in_sizes[2] / NOFF;
    const int nt = (N + TR - 1) / TR;                       // 64-row tiles (3125)

    const size_t fb_bytes  = (size_t)(N + 1) * 64 * sizeof(unsigned short); // +zero row
    const size_t wt_bytes  = 27 * 64 * 64 * sizeof(unsigned short);
    const size_t tab_bytes = (size_t)NOFF * nt * TR * sizeof(int);

    if (ws_size < fb_bytes + wt_bytes + tab_bytes) {
        dim3 blk(256);
        dim3 gc((N + 255) / 256, 1);
        spconv_fb<0><<<gc, blk, 0, stream>>>(feats, W, nullptr, nullptr, out, N);
        dim3 go((P + 255) / 256, NOFF);
        spconv_fb<1><<<go, blk, 0, stream>>>(feats, W, imap, omap, out, P);
        return;
    }

    unsigned short* fbp = (unsigned short*)d_ws;
    unsigned short* Wt  = (unsigned short*)((char*)d_ws + fb_bytes);
    int* tab            = (int*)((char*)d_ws + fb_bytes + wt_bytes);

    const int nf = N * 64;
    prep_feats<<<(nf / 8 + 255) / 256, 256, 0, stream>>>(feats, fbp, nf);
    hipMemsetAsync(fbp + (size_t)N * 64, 0, 128, stream);   // zero row N
    prep_wt<<<27, 256, 0, stream>>>(W, Wt);
    const int n4 = (int)(tab_bytes / 16);
    prep_tab_init<<<(n4 + 255) / 256, 256, 0, stream>>>((int4*)tab, n4, N);
    prep_tab<<<dim3((P + 255) / 256, NOFF), 256, 0, stream>>>(imap, omap, P, nt, tab);

    spconv_v6<<<(nt + 3) / 4, 256, 0, stream>>>(fbp, Wt, tab, out, N, nt);
}